// Round 13
// baseline (375.226 us; speedup 1.0000x reference)
//
#include <hip/hip_runtime.h>
#include <hip/hip_bf16.h>

#define GAS __attribute__((address_space(1)))
#define LAS __attribute__((address_space(3)))

typedef __attribute__((ext_vector_type(8))) short   bf16x8;
typedef __attribute__((ext_vector_type(4))) float   f32x4;
typedef __attribute__((ext_vector_type(16))) float  f32x16;
typedef __attribute__((ext_vector_type(4))) float   f4;
typedef __attribute__((ext_vector_type(8))) short   s8v;
typedef __attribute__((ext_vector_type(4))) unsigned int u32x4;

#define NB  64
#define NS  512
#define ND  768
#define NH  12
#define NHS 64
#define NM  (NB*NS)    /* 32768 */

// 0.125 * log2(e): folded into Q so softmax uses exp2 directly
#define QSCALE 0.18033688011112042f

__device__ __forceinline__ unsigned short f2bf(float x){
  unsigned int u = __float_as_uint(x);
  u += 0x7fffu + ((u >> 16) & 1u);       // round-to-nearest-even
  return (unsigned short)(u >> 16);
}

__device__ __forceinline__ f32x4 mfma16(bf16x8 a, bf16x8 b, f32x4 c){
  return __builtin_amdgcn_mfma_f32_16x16x32_bf16(a, b, c, 0, 0, 0);
}

__device__ __forceinline__ f32x16 mfma32(bf16x8 a, bf16x8 b, f32x16 c){
  return __builtin_amdgcn_mfma_f32_32x32x16_bf16(a, b, c, 0, 0, 0);
}

__device__ __forceinline__ unsigned int cvtpk(float lo, float hi){
  unsigned int r;
  asm("v_cvt_pk_bf16_f32 %0, %1, %2" : "=v"(r) : "v"(lo), "v"(hi));
  return r;
}

__device__ __forceinline__ bf16x8 u2b(u32x4 u){
  union { u32x4 a; bf16x8 b; } c; c.a = u; return c.b;
}

// ---------------- combined convert: activations fp32->bf16 + W -> Wt[n][k] bf16
__global__ void cvt_all(const float* __restrict__ from_t, const float* __restrict__ to_t,
                        const float* __restrict__ Wq, const float* __restrict__ Wk,
                        const float* __restrict__ Wv,
                        short* __restrict__ fb, short* __restrict__ tb,
                        short* __restrict__ Wt){
  int bid = blockIdx.x;
  if (bid < 24576){                                // activations: 8 elems/thread
    int v = bid * 256 + threadIdx.x;
    const int NG = NM * ND / 8;                    // 3145728 per tensor
    const float* s; short* d;
    if (v < NG){ s = from_t; d = fb; } else { s = to_t; d = tb; v -= NG; }
    f4 a = ((const f4*)s)[(long)v * 2];
    f4 b = ((const f4*)s)[(long)v * 2 + 1];
    s8v o;
    o[0]=(short)f2bf(a[0]); o[1]=(short)f2bf(a[1]); o[2]=(short)f2bf(a[2]); o[3]=(short)f2bf(a[3]);
    o[4]=(short)f2bf(b[0]); o[5]=(short)f2bf(b[1]); o[6]=(short)f2bf(b[2]); o[7]=(short)f2bf(b[3]);
    ((s8v*)d)[v] = o;
  } else {                                         // weights: transpose + convert
    int i = (bid - 24576) * 256 + threadIdx.x;     // 0 .. 3*768*768-1
    int mat = i / (ND*ND);
    int rem = i - mat * (ND*ND);
    int k = rem / ND;
    int n = rem - k * ND;
    const float* W = (mat == 0) ? Wq : (mat == 1 ? Wk : Wv);
    Wt[(long)mat*ND*ND + (long)n*ND + k] = (short)f2bf(W[rem]);
  }
}

// ---------------- fused QKV GEMM v6 — m97 structure: 128x128 tile, 4 waves,
// BK=64, SINGLE-buffered 32 KB LDS (3-5 blocks/CU; inter-block overlap absorbs
// the barrier drain — the proven 874-912 TF structure), global_load_lds both
// operands, 2 syncthreads per K-step, LDS-shuffle epilogue. ----------
__global__ __launch_bounds__(256)
void qkv_gemm(const short* __restrict__ Xf, const short* __restrict__ Xt,
              const short* __restrict__ Wt,
              const float* __restrict__ bq, const float* __restrict__ bk,
              const float* __restrict__ bv,
              short* __restrict__ Qw, short* __restrict__ Kw, short* __restrict__ Vtw){
  __shared__ short smem[16384];   // 32 KB: A @ 0 (16 KB), B @ 8192 shorts

  int bid = blockIdx.x;                       // 4608 blocks, %8==0
  int wg  = (bid & 7) * 576 + (bid >> 3);     // XCD-contiguous chunks
  int mat = wg / 1536;
  int r   = wg - mat * 1536;
  int mt  = r / 6;
  int nt  = r - mt * 6;                       // nt fastest: neighbors share A-panel

  const short* A  = (mat == 0) ? Xf : Xt;
  const short* Wp = Wt + (long)mat * ND * ND;

  int t_ = threadIdx.x, wv = t_ >> 6, l = t_ & 63, g = l >> 4, c = l & 15;
  int wm = wv >> 1, wn = wv & 1;              // 2x2 waves, 64x64 per wave
  int m0 = mt * 128, n0 = nt * 128;

  // stage K-tile kt: A+B, 128 rows x 8 slots of 16B each side, 8 glds/thread
  auto stage = [&](int kt){
    #pragma unroll
    for (int it = 0; it < 4; ++it){
      int idx = it * 256 + t_;                // 0..1023
      int row = idx >> 3, slot = idx & 7;     // 128 rows x 8 slots (8 bf16)
      int kc = kt * 64 + ((slot ^ (row & 7)) << 3);
      const short* ga = A + (long)(m0 + row) * ND + kc;
      __builtin_amdgcn_global_load_lds((const GAS unsigned int*)ga,
                                       (LAS unsigned int*)(smem + idx * 8), 16, 0, 0);
      const short* gb = Wp + (long)(n0 + row) * ND + kc;
      __builtin_amdgcn_global_load_lds((const GAS unsigned int*)gb,
                                       (LAS unsigned int*)(smem + 8192 + idx * 8), 16, 0, 0);
    }
  };

  f32x4 zero = {0.f, 0.f, 0.f, 0.f};
  f32x4 acc[4][4];
  #pragma unroll
  for (int i = 0; i < 4; ++i)
    #pragma unroll
    for (int j = 0; j < 4; ++j) acc[i][j] = zero;

  stage(0);
  for (int kt = 0; kt < 12; ++kt){
    __syncthreads();                          // tile kt landed (vmcnt0 drain)
    bf16x8 af[4][2], bfr[4][2];
    #pragma unroll
    for (int ms = 0; ms < 4; ++ms){
      int row = wm * 64 + ms * 16 + c;
      #pragma unroll
      for (int kk = 0; kk < 2; ++kk)
        af[ms][kk] = *(const bf16x8*)(smem + row * 64 + (((kk * 4 + g) ^ (row & 7)) << 3));
    }
    #pragma unroll
    for (int ns = 0; ns < 4; ++ns){
      int row = wn * 64 + ns * 16 + c;
      #pragma unroll
      for (int kk = 0; kk < 2; ++kk)
        bfr[ns][kk] = *(const bf16x8*)(smem + 8192 + row * 64 + (((kk * 4 + g) ^ (row & 7)) << 3));
    }
    #pragma unroll
    for (int kk = 0; kk < 2; ++kk)
      #pragma unroll
      for (int ms = 0; ms < 4; ++ms)
        #pragma unroll
        for (int ns = 0; ns < 4; ++ns)
          acc[ms][ns] = mfma16(af[ms][kk], bfr[ns][kk], acc[ms][ns]);
    __syncthreads();                          // all reads of tile kt done
    if (kt < 11) stage(kt + 1);               // overwrite buffer
  }

  // ---- epilogue: wave-private 8KB LDS chunk -> coalesced 16B stores
  int n0g = n0 + wn * 64;                    // 64 cols = exactly one head
  const float* bias = (mat == 0) ? bq : (mat == 1 ? bk : bv);
  float bb[4];
  #pragma unroll
  for (int ns = 0; ns < 4; ++ns) bb[ns] = bias[n0g + ns * 16 + c];
  short* chunk = smem + wv * 4096;           // 8 KB per wave (32 KB total)
  int hq = n0g >> 6;
  int mbase = m0 + wm * 64;                  // 64-aligned, never crosses b
  int b = mbase >> 9, s0 = mbase & 511;

  if (mat < 2){
    short* O = (mat == 0) ? Qw : Kw;
    float scl = (mat == 0) ? QSCALE : 1.0f;
    #pragma unroll
    for (int msl = 0; msl < 4; ++msl){
      #pragma unroll
      for (int ns = 0; ns < 4; ++ns){
        int col = ns * 16 + c;               // hs
        #pragma unroll
        for (int i = 0; i < 4; ++i){
          int row = msl * 16 + g * 4 + i;    // s-local 0..63
          chunk[row * 64 + (((col >> 3) ^ (row & 7)) << 3) + (col & 7)] =
              (short)f2bf((acc[msl][ns][i] + bb[ns]) * scl);
        }
      }
    }
    asm volatile("s_waitcnt lgkmcnt(0)" ::: "memory");
    __builtin_amdgcn_sched_barrier(0);
    #pragma unroll
    for (int rr = 0; rr < 8; ++rr){
      int row = rr * 8 + (l >> 3);           // 0..63, all 64 rows
      int slot = l & 7;
      bf16x8 v = *(const bf16x8*)(chunk + row * 64 + ((slot ^ (row & 7)) << 3));
      *(bf16x8*)(O + (((long)(b * NH + hq) * NS + s0 + row) << 6) + slot * 8) = v;
    }
  } else {
    #pragma unroll
    for (int msl = 0; msl < 4; ++msl){
      #pragma unroll
      for (int ns = 0; ns < 4; ++ns){
        int hs = ns * 16 + c;                // row 0..63
        #pragma unroll
        for (int i = 0; i < 4; ++i){
          int col = msl * 16 + g * 4 + i;    // s-local 0..63
          chunk[hs * 64 + (((col >> 3) ^ (hs & 7)) << 3) + (col & 7)] =
              (short)f2bf(acc[msl][ns][i] + bb[ns]);
        }
      }
    }
    asm volatile("s_waitcnt lgkmcnt(0)" ::: "memory");
    __builtin_amdgcn_sched_barrier(0);
    #pragma unroll
    for (int rr = 0; rr < 8; ++rr){
      int hs = rr * 8 + (l >> 3);
      int slot = l & 7;
      bf16x8 v = *(const bf16x8*)(chunk + hs * 64 + ((slot ^ (hs & 7)) << 3));
      *(bf16x8*)(Vtw + (long)((b * NH + hq) * 64 + hs) * NS + s0 + slot * 8) = v;
    }
  }
}

// ---------------- attention v3: 32x32 MFMA, swapped operands, P in registers.
// One (b,h) per block, 8 waves; each wave: 2 tiles of 32 q-rows, online softmax
// over 16 chunks of 32 keys. (unchanged — passing) --------
__global__ __launch_bounds__(512, 1)
void attn_kernel(const short* __restrict__ Qw, const short* __restrict__ Kw,
                 const short* __restrict__ Vtw, float* __restrict__ out){
  extern __shared__ char smem[];
  short* Ks = (short*)smem;              // [512][64] bf16, swizzled rows 128B, 64 KB
  short* Vs = (short*)(smem + 65536);    // [64][512] bf16, swizzled rows 1KB, 64 KB

  int bh = blockIdx.x;                   // 768 blocks
  int t = threadIdx.x, wv = t >> 6, l = t & 63;
  int lam = l & 31, hi = l >> 5;
  int r7 = lam & 7;

  const short* Kb = Kw  + (long)bh * NS * NHS;
  const short* Vb = Vtw + (long)bh * NS * NHS;

  // stage K [key][d] and Vt [d][key] once, 128 chunks of 1KB over 8 waves
  #pragma unroll
  for (int it = 0; it < 8; ++it){
    int chunk = it * 8 + wv;             // wave-uniform, 0..63
    {
      int idx = chunk * 64 + l;
      int row = idx >> 3, slot = idx & 7;
      const short* gk = Kb + row * 64 + ((slot ^ (row & 7)) * 8);
      __builtin_amdgcn_global_load_lds((const GAS unsigned int*)gk,
                                       (LAS unsigned int*)(Ks + chunk * 512), 16, 0, 0);
    }
    {
      int row = chunk, slot = l;         // one chunk = one d-row
      const short* gv = Vb + (long)row * NS + (((slot & 56) | ((slot & 7) ^ (row & 7))) * 8);
      __builtin_amdgcn_global_load_lds((const GAS unsigned int*)gv,
                                       (LAS unsigned int*)(Vs + chunk * 512), 16, 0, 0);
    }
  }
  __syncthreads();

  int b = bh / NH, h = bh - b * NH;
  float* outb = out + (long)b * NS * ND + (long)h * 64;

  for (int qt = 0; qt < 2; ++qt){
    int q0 = wv * 64 + qt * 32;
    // Q as B-operand: B[k=hi*8+j][col=q=lam], d = dk*16 + hi*8 + j
    const short* Qb = Qw + (((long)bh * NS + q0 + lam) << 6) + hi * 8;
    bf16x8 qf[4];
    #pragma unroll
    for (int dk = 0; dk < 4; ++dk) qf[dk] = *(const bf16x8*)(Qb + dk * 16);

    f32x16 o0, o1;                       // O[q=q0+lam][d=(reg&3)+8*(reg>>2)+4*hi+32*dh]
    #pragma unroll
    for (int j = 0; j < 16; ++j){ o0[j] = 0.f; o1[j] = 0.f; }
    float m_run = -1e30f, lsum = 0.f;

    #pragma unroll
    for (int ch = 0; ch < 16; ++ch){
      // ---- QK^T (swapped): s[reg] = S[key=ch*32+(reg&3)+8*(reg>>2)+4*hi][q=q0+lam]
      f32x16 s;
      #pragma unroll
      for (int j = 0; j < 16; ++j) s[j] = 0.f;
      const char* kbase = (const char*)Ks + (ch * 32 + lam) * 128;
      #pragma unroll
      for (int dk = 0; dk < 4; ++dk){
        bf16x8 kf = *(const bf16x8*)(kbase + (((hi + 2 * dk) ^ r7) << 4));
        s = mfma32(kf, qf[dk], s);
      }

      // ---- online softmax (defer-max, THR=8), per-lane q = lam
      float t8[8], t4[4];
      #pragma unroll
      for (int j = 0; j < 8; ++j) t8[j] = fmaxf(s[j], s[j + 8]);
      #pragma unroll
      for (int j = 0; j < 4; ++j) t4[j] = fmaxf(t8[j], t8[j + 4]);
      float m1 = fmaxf(fmaxf(t4[0], t4[1]), fmaxf(t4[2], t4[3]));
      float pmax = fmaxf(m1, __shfl_xor(m1, 32));
      if (__any(pmax > m_run + 8.0f)){
        float mnew = fmaxf(m_run, pmax);
        float cf = exp2f(m_run - mnew);
        lsum *= cf;
        #pragma unroll
        for (int j = 0; j < 16; ++j){ o0[j] *= cf; o1[j] *= cf; }
        m_run = mnew;
      }
      float p[16];
      #pragma unroll
      for (int j = 0; j < 16; ++j) p[j] = exp2f(s[j] - m_run);
      float a8[8], a4[4];
      #pragma unroll
      for (int j = 0; j < 8; ++j) a8[j] = p[j] + p[j + 8];
      #pragma unroll
      for (int j = 0; j < 4; ++j) a4[j] = a8[j] + a8[j + 4];
      lsum += (a4[0] + a4[1]) + (a4[2] + a4[3]);

      // ---- P -> bf16 fragments, single-partner exchange (lane ^ 32)
      unsigned int w[8];
      #pragma unroll
      for (int rr = 0; rr < 8; ++rr) w[rr] = cvtpk(p[2 * rr], p[2 * rr + 1]);
      unsigned int y0 = (unsigned int)__shfl_xor((int)(hi ? w[0] : w[2]), 32);
      unsigned int y1 = (unsigned int)__shfl_xor((int)(hi ? w[1] : w[3]), 32);
      unsigned int y2 = (unsigned int)__shfl_xor((int)(hi ? w[4] : w[6]), 32);
      unsigned int y3 = (unsigned int)__shfl_xor((int)(hi ? w[5] : w[7]), 32);
      u32x4 fa, fb;
      if (hi){
        fa[0] = y0;   fa[1] = y1;   fa[2] = w[2]; fa[3] = w[3];   // keys 8..15
        fb[0] = y2;   fb[1] = y3;   fb[2] = w[6]; fb[3] = w[7];   // keys 24..31
      } else {
        fa[0] = w[0]; fa[1] = w[1]; fa[2] = y0;   fa[3] = y1;     // keys 0..7
        fb[0] = w[4]; fb[1] = w[5]; fb[2] = y2;   fb[3] = y3;     // keys 16..23
      }
      bf16x8 pa = u2b(fa), pb = u2b(fb);

      // ---- PV (swapped): o[dh] += mfma32(V^T-frag, P-frag)
      const char* vb0 = (const char*)Vs + lam * 1024;          // d = lam
      const char* vb1 = (const char*)Vs + (32 + lam) * 1024;   // d = 32+lam
      int sl0 = ch * 4 + hi, sl1 = ch * 4 + 2 + hi;
      int sw0 = ((sl0 & 56) | ((sl0 & 7) ^ r7)) << 4;
      int sw1 = ((sl1 & 56) | ((sl1 & 7) ^ r7)) << 4;
      bf16x8 v00 = *(const bf16x8*)(vb0 + sw0);
      bf16x8 v01 = *(const bf16x8*)(vb0 + sw1);
      bf16x8 v10 = *(const bf16x8*)(vb1 + sw0);
      bf16x8 v11 = *(const bf16x8*)(vb1 + sw1);
      o0 = mfma32(v00, pa, o0);
      o0 = mfma32(v01, pb, o0);
      o1 = mfma32(v10, pa, o1);
      o1 = mfma32(v11, pb, o1);
    }

    // ---- epilogue: combine l across partner, deferred 1/sum, float4 stores
    float lt = lsum + __shfl_xor(lsum, 32);
    float invl = 1.0f / lt;
    float* orow = outb + (long)(q0 + lam) * ND;
    #pragma unroll
    for (int r = 0; r < 4; ++r){
      f4 u0, u1;
      #pragma unroll
      for (int jj = 0; jj < 4; ++jj){
        u0[jj] = o0[4 * r + jj] * invl;
        u1[jj] = o1[4 * r + jj] * invl;
      }
      *(f4*)(orow + 4 * hi + 8 * r)      = u0;   // d = 4hi+8r+{0..3}
      *(f4*)(orow + 32 + 4 * hi + 8 * r) = u1;   // d = 32+4hi+8r+{0..3}
    }
  }
}

// ---------------- launch ----------------
extern "C" void kernel_launch(void* const* d_in, const int* in_sizes, int n_in,
                              void* d_out, int out_size, void* d_ws, size_t ws_size,
                              hipStream_t stream){
  const float* from_t = (const float*)d_in[0];
  const float* to_t   = (const float*)d_in[1];
  const float* Wq = (const float*)d_in[2];
  const float* bq = (const float*)d_in[3];
  const float* Wk = (const float*)d_in[4];
  const float* bk = (const float*)d_in[5];
  const float* Wv = (const float*)d_in[6];
  const float* bv = (const float*)d_in[7];

  short* fb  = (short*)d_ws;                 // 25165824 bf16
  short* tb  = fb  + 25165824;               // 25165824
  short* Wt  = tb  + 25165824;               // 1769472
  short* Qw  = Wt  + 1769472;                // 25165824
  short* Kw  = Qw  + 25165824;               // 25165824
  short* Vtw = Kw  + 25165824;               // 25165824  (total ~243 MB)

  cvt_all<<<31488, 256, 0, stream>>>(from_t, to_t, Wq, Wk, Wv, fb, tb, Wt);
  qkv_gemm<<<4608, 256, 0, stream>>>(fb, tb, Wt, bq, bk, bv, Qw, Kw, Vtw);
  attn_kernel<<<768, 512, 131072, stream>>>(Qw, Kw, Vtw, (float*)d_out);
}

// Round 14
// 328.466 us; speedup vs baseline: 1.1424x; 1.1424x over previous
//
#include <hip/hip_runtime.h>
#include <hip/hip_bf16.h>

#define GAS __attribute__((address_space(1)))
#define LAS __attribute__((address_space(3)))

typedef __attribute__((ext_vector_type(8))) short   bf16x8;
typedef __attribute__((ext_vector_type(4))) float   f32x4;
typedef __attribute__((ext_vector_type(16))) float  f32x16;
typedef __attribute__((ext_vector_type(4))) float   f4;
typedef __attribute__((ext_vector_type(8))) short   s8v;
typedef __attribute__((ext_vector_type(4))) unsigned int u32x4;

#define NB  64
#define NS  512
#define ND  768
#define NH  12
#define NHS 64
#define NM  (NB*NS)    /* 32768 */

// 0.125 * log2(e): folded into Q so softmax uses exp2 directly
#define QSCALE 0.18033688011112042f

__device__ __forceinline__ unsigned short f2bf(float x){
  unsigned int u = __float_as_uint(x);
  u += 0x7fffu + ((u >> 16) & 1u);       // round-to-nearest-even
  return (unsigned short)(u >> 16);
}

__device__ __forceinline__ f32x4 mfma16(bf16x8 a, bf16x8 b, f32x4 c){
  return __builtin_amdgcn_mfma_f32_16x16x32_bf16(a, b, c, 0, 0, 0);
}

__device__ __forceinline__ f32x16 mfma32(bf16x8 a, bf16x8 b, f32x16 c){
  return __builtin_amdgcn_mfma_f32_32x32x16_bf16(a, b, c, 0, 0, 0);
}

__device__ __forceinline__ unsigned int cvtpk(float lo, float hi){
  unsigned int r;
  asm("v_cvt_pk_bf16_f32 %0, %1, %2" : "=v"(r) : "v"(lo), "v"(hi));
  return r;
}

__device__ __forceinline__ bf16x8 u2b(u32x4 u){
  union { u32x4 a; bf16x8 b; } c; c.a = u; return c.b;
}

// ---------------- combined convert: activations fp32->bf16 + W -> Wt[n][k] bf16
__global__ void cvt_all(const float* __restrict__ from_t, const float* __restrict__ to_t,
                        const float* __restrict__ Wq, const float* __restrict__ Wk,
                        const float* __restrict__ Wv,
                        short* __restrict__ fb, short* __restrict__ tb,
                        short* __restrict__ Wt){
  int bid = blockIdx.x;
  if (bid < 24576){                                // activations: 8 elems/thread
    int v = bid * 256 + threadIdx.x;
    const int NG = NM * ND / 8;                    // 3145728 per tensor
    const float* s; short* d;
    if (v < NG){ s = from_t; d = fb; } else { s = to_t; d = tb; v -= NG; }
    f4 a = ((const f4*)s)[(long)v * 2];
    f4 b = ((const f4*)s)[(long)v * 2 + 1];
    s8v o;
    o[0]=(short)f2bf(a[0]); o[1]=(short)f2bf(a[1]); o[2]=(short)f2bf(a[2]); o[3]=(short)f2bf(a[3]);
    o[4]=(short)f2bf(b[0]); o[5]=(short)f2bf(b[1]); o[6]=(short)f2bf(b[2]); o[7]=(short)f2bf(b[3]);
    ((s8v*)d)[v] = o;
  } else {                                         // weights: transpose + convert
    int i = (bid - 24576) * 256 + threadIdx.x;     // 0 .. 3*768*768-1
    int mat = i / (ND*ND);
    int rem = i - mat * (ND*ND);
    int k = rem / ND;
    int n = rem - k * ND;
    const float* W = (mat == 0) ? Wq : (mat == 1 ? Wk : Wv);
    Wt[(long)mat*ND*ND + (long)n*ND + k] = (short)f2bf(W[rem]);
  }
}

// ---------------- fused QKV GEMM v7 — true 8-phase template: 256x256 tile,
// BK=64, 8 waves, 2-slot 128KB LDS dbuf. Each phase = one BLOCK-level 128x128
// C-quadrant (wave sub-tile 64x32) -> consumes ONE A-half + ONE B-half.
// Stage exactly 1 half-tile/phase at lookahead 4; vmcnt(4) per phase (tail
// 2/0); setprio around the 16-MFMA cluster. ----------
__global__ __launch_bounds__(512)
void qkv_gemm(const short* __restrict__ Xf, const short* __restrict__ Xt,
              const short* __restrict__ Wt,
              const float* __restrict__ bq, const float* __restrict__ bk,
              const float* __restrict__ bv,
              short* __restrict__ Qw, short* __restrict__ Kw, short* __restrict__ Vtw){
  __shared__ short smem[65536];   // 128 KB: A slot s @ s*16384, B slot s @ 32768+s*16384

  int bid = blockIdx.x;                       // 1152 blocks, %8==0
  int wg  = (bid & 7) * 144 + (bid >> 3);     // XCD-contiguous chunks
  int mat = wg / 384;
  int r   = wg - mat * 384;
  int mt  = r / 3;
  int nt  = r - mt * 3;                       // nt fastest: neighbors share A-panel

  const short* A  = (mat == 0) ? Xf : Xt;
  const short* Wp = Wt + (long)mat * ND * ND;

  int t_ = threadIdx.x, wv = t_ >> 6, l = t_ & 63, lg = l >> 4, cc = l & 15;
  int wmh = wv >> 2, wnh = wv & 3;            // wave sub-tile pos within quadrant
  int m0 = mt * 256, n0 = nt * 256;

  // stage one half-tile: ty 0=A rows0-127, 1=B rows0-127, 2=A rows128-255, 3=B rows128-255
  // (stream order per tile: A0,B0,A1,B1 = exactly the first-need order of quadrants)
  auto stage_half = [&](int kt2, int ty){
    int rbase = (ty >> 1) * 128;
    short* base;
    const short* src;
    int r0;
    if ((ty & 1) == 0){ base = smem + (kt2 & 1) * 16384 + rbase * 64;         src = A;  r0 = m0; }
    else              { base = smem + 32768 + (kt2 & 1) * 16384 + rbase * 64; src = Wp; r0 = n0; }
    #pragma unroll
    for (int j = 0; j < 2; ++j){
      int idx = j * 512 + t_;                 // 0..1023 -> 128 rows x 8 slots of 16B
      int row = idx >> 3, slot = idx & 7;
      const short* gp = src + (long)(r0 + rbase + row) * ND + kt2 * 64 + ((slot ^ (row & 7)) << 3);
      __builtin_amdgcn_global_load_lds((const GAS unsigned int*)gp,
                                       (LAS unsigned int*)(base + idx * 8), 16, 0, 0);
    }
  };

  f32x4 zero = {0.f, 0.f, 0.f, 0.f};
  f32x4 acc[2][2][4][2];                      // [qm][qn][fr][fc], all static-indexed
  #pragma unroll
  for (int a1 = 0; a1 < 2; ++a1)
    #pragma unroll
    for (int a2 = 0; a2 < 2; ++a2)
      #pragma unroll
      for (int a3 = 0; a3 < 4; ++a3)
        #pragma unroll
        for (int a4 = 0; a4 < 2; ++a4) acc[a1][a2][a3][a4] = zero;

  bf16x8 afr[4][2], bfr[2][2];
  int gph = 0;                                // global phase counter 0..47

// one phase: quadrant (qm,qn) of tile kt over K=64. RA/RB: load frags or reuse.
#define PHASE(kt, qm, qn, RA, RB) do {                                          \
  const short* As_ = smem + ((kt) & 1) * 16384;                                 \
  const short* Bs_ = smem + 32768 + ((kt) & 1) * 16384;                         \
  if (RA){                                                                      \
    _Pragma("unroll")                                                           \
    for (int fr = 0; fr < 4; ++fr){                                             \
      int ar = (qm) * 128 + wmh * 64 + fr * 16 + cc;                            \
      afr[fr][0] = *(const bf16x8*)(As_ + ar * 64 + (((0 + lg) ^ (ar & 7)) << 3)); \
      afr[fr][1] = *(const bf16x8*)(As_ + ar * 64 + (((4 + lg) ^ (ar & 7)) << 3)); \
    }                                                                           \
  }                                                                             \
  if (RB){                                                                      \
    _Pragma("unroll")                                                           \
    for (int fc = 0; fc < 2; ++fc){                                             \
      int br = (qn) * 128 + wnh * 32 + fc * 16 + cc;                            \
      bfr[fc][0] = *(const bf16x8*)(Bs_ + br * 64 + (((0 + lg) ^ (br & 7)) << 3)); \
      bfr[fc][1] = *(const bf16x8*)(Bs_ + br * 64 + (((4 + lg) ^ (br & 7)) << 3)); \
    }                                                                           \
  }                                                                             \
  { int s_ = gph + 4; if (s_ < 48) stage_half(s_ >> 2, s_ & 3); }               \
  __builtin_amdgcn_s_barrier();                                                 \
  asm volatile("s_waitcnt lgkmcnt(0)" ::: "memory");                            \
  __builtin_amdgcn_sched_barrier(0);                                            \
  __builtin_amdgcn_s_setprio(1);                                                \
  _Pragma("unroll")                                                             \
  for (int fr = 0; fr < 4; ++fr)                                                \
    _Pragma("unroll")                                                           \
    for (int fc = 0; fc < 2; ++fc){                                             \
      acc[qm][qn][fr][fc] = mfma16(afr[fr][0], bfr[fc][0], acc[qm][qn][fr][fc]);\
      acc[qm][qn][fr][fc] = mfma16(afr[fr][1], bfr[fc][1], acc[qm][qn][fr][fc]);\
    }                                                                           \
  __builtin_amdgcn_s_setprio(0);                                                \
  if (gph <= 43)      asm volatile("s_waitcnt vmcnt(4)" ::: "memory");          \
  else if (gph == 44) asm volatile("s_waitcnt vmcnt(2)" ::: "memory");          \
  else if (gph == 45) asm volatile("s_waitcnt vmcnt(0)" ::: "memory");          \
  __builtin_amdgcn_s_barrier();                                                 \
  ++gph;                                                                        \
} while (0)

  // prologue: tile 0's 4 half-tiles in flight; A0,B0 landed before phase 0
  stage_half(0, 0); stage_half(0, 1); stage_half(0, 2); stage_half(0, 3);
  asm volatile("s_waitcnt vmcnt(4)" ::: "memory");   // A0,B0 landed; A1,B1 pending
  __builtin_amdgcn_s_barrier();

  for (int it2 = 0; it2 < 6; ++it2){
    int k0 = it2 * 2, k1 = k0 + 1;
    PHASE(k0, 0, 0, 1, 1);   // 12 ds_read
    PHASE(k0, 1, 0, 1, 0);   // 8  (B reused)
    PHASE(k0, 1, 1, 0, 1);   // 4  (A reused)
    PHASE(k0, 0, 1, 1, 0);   // 8  (B reused)
    PHASE(k1, 0, 0, 1, 1);
    PHASE(k1, 1, 0, 1, 0);
    PHASE(k1, 1, 1, 0, 1);
    PHASE(k1, 0, 1, 1, 0);
  }
#undef PHASE

  // ---- epilogue: per-wave 16KB LDS chunk, 4 regions of 64x32 (or 32x64 for V)
  const float* bias = (mat == 0) ? bq : (mat == 1 ? bk : bv);
  float bb[2][2];
  #pragma unroll
  for (int qn = 0; qn < 2; ++qn)
    #pragma unroll
    for (int fc = 0; fc < 2; ++fc)
      bb[qn][fc] = bias[n0 + qn * 128 + wnh * 32 + fc * 16 + cc];
  short* chunk = smem + wv * 8192;            // 16 KB per wave

  if (mat < 2){
    short* O = (mat == 0) ? Qw : Kw;
    float scl = (mat == 0) ? QSCALE : 1.0f;
    #pragma unroll
    for (int qm = 0; qm < 2; ++qm){
      int mr0 = m0 + qm * 128 + wmh * 64;
      int b = mr0 >> 9, s0r = mr0 & 511;
      #pragma unroll
      for (int qn = 0; qn < 2; ++qn){
        int nc0 = n0 + qn * 128 + wnh * 32;
        int hq = nc0 >> 6, hs0 = nc0 & 63;
        asm volatile("s_waitcnt lgkmcnt(0)" ::: "memory");   // WAR on chunk
        #pragma unroll
        for (int fr = 0; fr < 4; ++fr)
          #pragma unroll
          for (int fc = 0; fc < 2; ++fc)
            #pragma unroll
            for (int i = 0; i < 4; ++i)
              chunk[(fr * 16 + lg * 4 + i) * 40 + fc * 16 + cc] =
                  (short)f2bf((acc[qm][qn][fr][fc][i] + bb[qn][fc]) * scl);
        asm volatile("s_waitcnt lgkmcnt(0)" ::: "memory");
        __builtin_amdgcn_sched_barrier(0);
        #pragma unroll
        for (int it = 0; it < 4; ++it){
          int idx = it * 64 + l;
          int row = idx >> 2, sl = idx & 3;    // 64 rows x 4 slots of 16B (32 cols)
          bf16x8 v = *(const bf16x8*)(chunk + row * 40 + sl * 8);
          *(bf16x8*)(O + (((long)(b * NH + hq) * NS + s0r + row) << 6) + hs0 + sl * 8) = v;
        }
      }
    }
  } else {
    #pragma unroll
    for (int qm = 0; qm < 2; ++qm){
      int mr0 = m0 + qm * 128 + wmh * 64;
      int b = mr0 >> 9, s0r = mr0 & 511;
      #pragma unroll
      for (int qn = 0; qn < 2; ++qn){
        int nc0 = n0 + qn * 128 + wnh * 32;
        int hq = nc0 >> 6, hs0 = nc0 & 63;
        asm volatile("s_waitcnt lgkmcnt(0)" ::: "memory");   // WAR on chunk
        #pragma unroll
        for (int fr = 0; fr < 4; ++fr)
          #pragma unroll
          for (int fc = 0; fc < 2; ++fc)
            #pragma unroll
            for (int i = 0; i < 4; ++i)
              chunk[(fc * 16 + cc) * 72 + fr * 16 + lg * 4 + i] =
                  (short)f2bf(acc[qm][qn][fr][fc][i] + bb[qn][fc]);
        asm volatile("s_waitcnt lgkmcnt(0)" ::: "memory");
        __builtin_amdgcn_sched_barrier(0);
        #pragma unroll
        for (int it = 0; it < 4; ++it){
          int idx = it * 64 + l;
          int row = idx >> 3, sl = idx & 7;    // 32 hs-rows x 8 slots of 16B (64 s)
          bf16x8 v = *(const bf16x8*)(chunk + row * 72 + sl * 8);
          *(bf16x8*)(Vtw + (long)((b * NH + hq) * 64 + hs0 + row) * NS + s0r + sl * 8) = v;
        }
      }
    }
  }
}

// ---------------- attention v3: 32x32 MFMA, swapped operands, P in registers.
// One (b,h) per block, 8 waves; each wave: 2 tiles of 32 q-rows, online softmax
// over 16 chunks of 32 keys. (unchanged — passing) --------
__global__ __launch_bounds__(512, 1)
void attn_kernel(const short* __restrict__ Qw, const short* __restrict__ Kw,
                 const short* __restrict__ Vtw, float* __restrict__ out){
  extern __shared__ char smem[];
  short* Ks = (short*)smem;              // [512][64] bf16, swizzled rows 128B, 64 KB
  short* Vs = (short*)(smem + 65536);    // [64][512] bf16, swizzled rows 1KB, 64 KB

  int bh = blockIdx.x;                   // 768 blocks
  int t = threadIdx.x, wv = t >> 6, l = t & 63;
  int lam = l & 31, hi = l >> 5;
  int r7 = lam & 7;

  const short* Kb = Kw  + (long)bh * NS * NHS;
  const short* Vb = Vtw + (long)bh * NS * NHS;

  // stage K [key][d] and Vt [d][key] once, 128 chunks of 1KB over 8 waves
  #pragma unroll
  for (int it = 0; it < 8; ++it){
    int chunk = it * 8 + wv;             // wave-uniform, 0..63
    {
      int idx = chunk * 64 + l;
      int row = idx >> 3, slot = idx & 7;
      const short* gk = Kb + row * 64 + ((slot ^ (row & 7)) * 8);
      __builtin_amdgcn_global_load_lds((const GAS unsigned int*)gk,
                                       (LAS unsigned int*)(Ks + chunk * 512), 16, 0, 0);
    }
    {
      int row = chunk, slot = l;         // one chunk = one d-row
      const short* gv = Vb + (long)row * NS + (((slot & 56) | ((slot & 7) ^ (row & 7))) * 8);
      __builtin_amdgcn_global_load_lds((const GAS unsigned int*)gv,
                                       (LAS unsigned int*)(Vs + chunk * 512), 16, 0, 0);
    }
  }
  __syncthreads();

  int b = bh / NH, h = bh - b * NH;
  float* outb = out + (long)b * NS * ND + (long)h * 64;

  for (int qt = 0; qt < 2; ++qt){
    int q0 = wv * 64 + qt * 32;
    // Q as B-operand: B[k=hi*8+j][col=q=lam], d = dk*16 + hi*8 + j
    const short* Qb = Qw + (((long)bh * NS + q0 + lam) << 6) + hi * 8;
    bf16x8 qf[4];
    #pragma unroll
    for (int dk = 0; dk < 4; ++dk) qf[dk] = *(const bf16x8*)(Qb + dk * 16);

    f32x16 o0, o1;                       // O[q=q0+lam][d=(reg&3)+8*(reg>>2)+4*hi+32*dh]
    #pragma unroll
    for (int j = 0; j < 16; ++j){ o0[j] = 0.f; o1[j] = 0.f; }
    float m_run = -1e30f, lsum = 0.f;

    #pragma unroll
    for (int ch = 0; ch < 16; ++ch){
      // ---- QK^T (swapped): s[reg] = S[key=ch*32+(reg&3)+8*(reg>>2)+4*hi][q=q0+lam]
      f32x16 s;
      #pragma unroll
      for (int j = 0; j < 16; ++j) s[j] = 0.f;
      const char* kbase = (const char*)Ks + (ch * 32 + lam) * 128;
      #pragma unroll
      for (int dk = 0; dk < 4; ++dk){
        bf16x8 kf = *(const bf16x8*)(kbase + (((hi + 2 * dk) ^ r7) << 4));
        s = mfma32(kf, qf[dk], s);
      }

      // ---- online softmax (defer-max, THR=8), per-lane q = lam
      float t8[8], t4[4];
      #pragma unroll
      for (int j = 0; j < 8; ++j) t8[j] = fmaxf(s[j], s[j + 8]);
      #pragma unroll
      for (int j = 0; j < 4; ++j) t4[j] = fmaxf(t8[j], t8[j + 4]);
      float m1 = fmaxf(fmaxf(t4[0], t4[1]), fmaxf(t4[2], t4[3]));
      float pmax = fmaxf(m1, __shfl_xor(m1, 32));
      if (__any(pmax > m_run + 8.0f)){
        float mnew = fmaxf(m_run, pmax);
        float cf = exp2f(m_run - mnew);
        lsum *= cf;
        #pragma unroll
        for (int j = 0; j < 16; ++j){ o0[j] *= cf; o1[j] *= cf; }
        m_run = mnew;
      }
      float p[16];
      #pragma unroll
      for (int j = 0; j < 16; ++j) p[j] = exp2f(s[j] - m_run);
      float a8[8], a4[4];
      #pragma unroll
      for (int j = 0; j < 8; ++j) a8[j] = p[j] + p[j + 8];
      #pragma unroll
      for (int j = 0; j < 4; ++j) a4[j] = a8[j] + a8[j + 4];
      lsum += (a4[0] + a4[1]) + (a4[2] + a4[3]);

      // ---- P -> bf16 fragments, single-partner exchange (lane ^ 32)
      unsigned int w[8];
      #pragma unroll
      for (int rr = 0; rr < 8; ++rr) w[rr] = cvtpk(p[2 * rr], p[2 * rr + 1]);
      unsigned int y0 = (unsigned int)__shfl_xor((int)(hi ? w[0] : w[2]), 32);
      unsigned int y1 = (unsigned int)__shfl_xor((int)(hi ? w[1] : w[3]), 32);
      unsigned int y2 = (unsigned int)__shfl_xor((int)(hi ? w[4] : w[6]), 32);
      unsigned int y3 = (unsigned int)__shfl_xor((int)(hi ? w[5] : w[7]), 32);
      u32x4 fa, fb;
      if (hi){
        fa[0] = y0;   fa[1] = y1;   fa[2] = w[2]; fa[3] = w[3];   // keys 8..15
        fb[0] = y2;   fb[1] = y3;   fb[2] = w[6]; fb[3] = w[7];   // keys 24..31
      } else {
        fa[0] = w[0]; fa[1] = w[1]; fa[2] = y0;   fa[3] = y1;     // keys 0..7
        fb[0] = w[4]; fb[1] = w[5]; fb[2] = y2;   fb[3] = y3;     // keys 16..23
      }
      bf16x8 pa = u2b(fa), pb = u2b(fb);

      // ---- PV (swapped): o[dh] += mfma32(V^T-frag, P-frag)
      const char* vb0 = (const char*)Vs + lam * 1024;          // d = lam
      const char* vb1 = (const char*)Vs + (32 + lam) * 1024;   // d = 32+lam
      int sl0 = ch * 4 + hi, sl1 = ch * 4 + 2 + hi;
      int sw0 = ((sl0 & 56) | ((sl0 & 7) ^ r7)) << 4;
      int sw1 = ((sl1 & 56) | ((sl1 & 7) ^ r7)) << 4;
      bf16x8 v00 = *(const bf16x8*)(vb0 + sw0);
      bf16x8 v01 = *(const bf16x8*)(vb0 + sw1);
      bf16x8 v10 = *(const bf16x8*)(vb1 + sw0);
      bf16x8 v11 = *(const bf16x8*)(vb1 + sw1);
      o0 = mfma32(v00, pa, o0);
      o0 = mfma32(v01, pb, o0);
      o1 = mfma32(v10, pa, o1);
      o1 = mfma32(v11, pb, o1);
    }

    // ---- epilogue: combine l across partner, deferred 1/sum, float4 stores
    float lt = lsum + __shfl_xor(lsum, 32);
    float invl = 1.0f / lt;
    float* orow = outb + (long)(q0 + lam) * ND;
    #pragma unroll
    for (int r = 0; r < 4; ++r){
      f4 u0, u1;
      #pragma unroll
      for (int jj = 0; jj < 4; ++jj){
        u0[jj] = o0[4 * r + jj] * invl;
        u1[jj] = o1[4 * r + jj] * invl;
      }
      *(f4*)(orow + 4 * hi + 8 * r)      = u0;   // d = 4hi+8r+{0..3}
      *(f4*)(orow + 32 + 4 * hi + 8 * r) = u1;   // d = 32+4hi+8r+{0..3}
    }
  }
}

// ---------------- launch ----------------
extern "C" void kernel_launch(void* const* d_in, const int* in_sizes, int n_in,
                              void* d_out, int out_size, void* d_ws, size_t ws_size,
                              hipStream_t stream){
  const float* from_t = (const float*)d_in[0];
  const float* to_t   = (const float*)d_in[1];
  const float* Wq = (const float*)d_in[2];
  const float* bq = (const float*)d_in[3];
  const float* Wk = (const float*)d_in[4];
  const float* bk = (const float*)d_in[5];
  const float* Wv = (const float*)d_in[6];
  const float* bv = (const float*)d_in[7];

  short* fb  = (short*)d_ws;                 // 25165824 bf16
  short* tb  = fb  + 25165824;               // 25165824
  short* Wt  = tb  + 25165824;               // 1769472
  short* Qw  = Wt  + 1769472;                // 25165824
  short* Kw  = Qw  + 25165824;               // 25165824
  short* Vtw = Kw  + 25165824;               // 25165824  (total ~243 MB)

  cvt_all<<<31488, 256, 0, stream>>>(from_t, to_t, Wq, Wk, Wv, fb, tb, Wt);
  qkv_gemm<<<1152, 512, 0, stream>>>(fb, tb, Wt, bq, bk, bv, Qw, Kw, Vtw);
  attn_kernel<<<768, 512, 131072, stream>>>(Qw, Kw, Vtw, (float*)d_out);
}

// Round 15
// 307.044 us; speedup vs baseline: 1.2221x; 1.0698x over previous
//
#include <hip/hip_runtime.h>
#include <hip/hip_bf16.h>

#define GAS __attribute__((address_space(1)))
#define LAS __attribute__((address_space(3)))

typedef __attribute__((ext_vector_type(8))) short   bf16x8;
typedef __attribute__((ext_vector_type(4))) float   f32x4;
typedef __attribute__((ext_vector_type(16))) float  f32x16;
typedef __attribute__((ext_vector_type(4))) float   f4;
typedef __attribute__((ext_vector_type(8))) short   s8v;
typedef __attribute__((ext_vector_type(4))) unsigned int u32x4;

#define NB  64
#define NS  512
#define ND  768
#define NH  12
#define NHS 64
#define NM  (NB*NS)    /* 32768 */

// 0.125 * log2(e): folded into Q so softmax uses exp2 directly
#define QSCALE 0.18033688011112042f

__device__ __forceinline__ unsigned short f2bf(float x){
  unsigned int u = __float_as_uint(x);
  u += 0x7fffu + ((u >> 16) & 1u);       // round-to-nearest-even
  return (unsigned short)(u >> 16);
}

__device__ __forceinline__ f32x4 mfma16(bf16x8 a, bf16x8 b, f32x4 c){
  return __builtin_amdgcn_mfma_f32_16x16x32_bf16(a, b, c, 0, 0, 0);
}

__device__ __forceinline__ f32x16 mfma32(bf16x8 a, bf16x8 b, f32x16 c){
  return __builtin_amdgcn_mfma_f32_32x32x16_bf16(a, b, c, 0, 0, 0);
}

__device__ __forceinline__ unsigned int cvtpk(float lo, float hi){
  unsigned int r;
  asm("v_cvt_pk_bf16_f32 %0, %1, %2" : "=v"(r) : "v"(lo), "v"(hi));
  return r;
}

__device__ __forceinline__ bf16x8 u2b(u32x4 u){
  union { u32x4 a; bf16x8 b; } c; c.a = u; return c.b;
}

// ---------------- W [k][n] fp32 -> Wt [mat][n][k] bf16 ----------------
__global__ void cvt_w(const float* __restrict__ Wq, const float* __restrict__ Wk,
                      const float* __restrict__ Wv, short* __restrict__ Wt){
  int i = blockIdx.x * 256 + threadIdx.x;          // 0 .. 3*768*768-1
  int mat = i / (ND*ND);
  int rem = i - mat * (ND*ND);
  int k = rem / ND;
  int n = rem - k * ND;
  const float* W = (mat == 0) ? Wq : (mat == 1 ? Wk : Wv);
  Wt[(long)mat*ND*ND + (long)n*ND + k] = (short)f2bf(W[rem]);
}

// ---------------- fused QKV GEMM (R7, validated 224us): cvt_x fused in. A read
// as fp32 from the original activations (reg-staged: load in phase-A of kt for
// kt+3, cvt_pk + ds_write in phase-A of kt+1); B via global_load_lds. 4-slot
// LDS ring, BK=32, counted vmcnt(8). ----------
__global__ __launch_bounds__(512, 2)
void qkv_gemm(const float* __restrict__ from_t, const float* __restrict__ to_t,
              const short* __restrict__ Wt,
              const float* __restrict__ bq, const float* __restrict__ bk,
              const float* __restrict__ bv,
              short* __restrict__ Qw, short* __restrict__ Kw, short* __restrict__ Vtw){
  __shared__ short smem[65536];   // 128 KB: A slots @ s*8192, B slots @ 32768 + s*8192

  int bid = blockIdx.x;                       // 1152 blocks, %8==0
  int wg  = (bid & 7) * 144 + (bid >> 3);     // XCD-contiguous chunks
  int mat = wg / 384;
  int r   = wg - mat * 384;
  int mt  = r / 3;
  int nt  = r - mt * 3;                       // nt fastest: neighbors share A-panel

  const float* Af = (mat == 0) ? from_t : to_t;
  const short* Wp = Wt + (long)mat * ND * ND;

  int t_ = threadIdx.x, wv = t_ >> 6, l = t_ & 63, g = l >> 4, c = l & 15;
  int wm = wv >> 2, wn = wv & 3;              // 2M x 4N waves, 128x64 per wave
  int m0 = mt * 256, n0 = nt * 256;

  f4 areg[4];                                 // in-flight A tile (fp32), 16 VGPR

  auto stageA_load = [&](int kt2){
    #pragma unroll
    for (int j = 0; j < 2; ++j){
      int idx = j * 512 + t_;                 // 0..1023
      int row = idx >> 2, slot = idx & 3;     // 256 rows x 4 slots (8 fp32 each)
      const float* gp = Af + (long)(m0 + row) * ND + kt2 * 32 + slot * 8;
      areg[j * 2]     = *(const f4*)(gp);
      areg[j * 2 + 1] = *(const f4*)(gp + 4);
    }
  };
  auto stageA_write = [&](int kt2){
    short* base = smem + (kt2 & 3) * 8192;
    #pragma unroll
    for (int j = 0; j < 2; ++j){
      int idx = j * 512 + t_;
      int row = idx >> 2, slot = idx & 3;
      int sw = slot ^ ((row >> 1) & 3);       // swizzled write (read side XORs same)
      u32x4 pk;
      pk[0] = cvtpk(areg[j * 2][0],     areg[j * 2][1]);
      pk[1] = cvtpk(areg[j * 2][2],     areg[j * 2][3]);
      pk[2] = cvtpk(areg[j * 2 + 1][0], areg[j * 2 + 1][1]);
      pk[3] = cvtpk(areg[j * 2 + 1][2], areg[j * 2 + 1][3]);
      *(bf16x8*)(base + row * 32 + sw * 8) = u2b(pk);
    }
  };
  auto stageB = [&](int kt2){
    short* base = smem + 32768 + (kt2 & 3) * 8192;
    #pragma unroll
    for (int j = 0; j < 2; ++j){
      int idx = j * 512 + t_;
      int row = idx >> 2, slot = idx & 3;
      const short* gp = Wp + (long)(n0 + row) * ND + kt2 * 32 + ((slot ^ ((row >> 1) & 3)) << 3);
      __builtin_amdgcn_global_load_lds((const GAS unsigned int*)gp,
                                       (LAS unsigned int*)(base + idx * 8), 16, 0, 0);
    }
  };

  f32x4 zero = {0.f, 0.f, 0.f, 0.f};
  f32x4 acc[8][4];
  #pragma unroll
  for (int i = 0; i < 8; ++i)
    #pragma unroll
    for (int j = 0; j < 4; ++j) acc[i][j] = zero;

  // prologue: B tiles 0,1,2 in flight; A tiles 0,1 written; A tile 2 in regs
  stageB(0);
  stageA_load(0);
  stageA_write(0);                            // compiler vmcnt-waits A0 (once)
  stageA_load(1);
  stageA_write(1);
  stageA_load(2);                             // held for kt=0's write
  stageB(1); stageB(2);
  asm volatile("s_waitcnt vmcnt(8)" ::: "memory");   // B(0) landed
  asm volatile("s_waitcnt lgkmcnt(0)" ::: "memory"); // A-writes drained
  __builtin_amdgcn_s_barrier();

  bf16x8 bfr[4];
  for (int kt = 0; kt < 24; ++kt){
    int sl = kt & 3;
    const short* Asl = smem + sl * 8192;
    const short* Bsl = smem + 32768 + sl * 8192;

    // ---- phase A (M-frags 0..3): 8 ds_read; write A(kt+2); issue A-loads(kt+3)
    bf16x8 af[4];
    #pragma unroll
    for (int i = 0; i < 4; ++i){
      int row = wm * 128 + i * 16 + c;
      af[i] = *(const bf16x8*)(Asl + row * 32 + ((g ^ ((row >> 1) & 3)) << 3));
    }
    #pragma unroll
    for (int ns = 0; ns < 4; ++ns){
      int row = wn * 64 + ns * 16 + c;
      bfr[ns] = *(const bf16x8*)(Bsl + row * 32 + ((g ^ ((row >> 1) & 3)) << 3));
    }
    if (kt < 22) stageA_write(kt + 2);
    if (kt < 21) stageA_load(kt + 3);
    __builtin_amdgcn_s_barrier();
    asm volatile("s_waitcnt lgkmcnt(0)" ::: "memory");
    __builtin_amdgcn_sched_barrier(0);
    __builtin_amdgcn_s_setprio(1);
    #pragma unroll
    for (int i = 0; i < 4; ++i)
      #pragma unroll
      for (int ns = 0; ns < 4; ++ns)
        acc[i][ns] = mfma16(af[i], bfr[ns], acc[i][ns]);
    __builtin_amdgcn_s_setprio(0);
    __builtin_amdgcn_s_barrier();

    // ---- phase B (M-frags 4..7): 4 ds_read + stage B(kt+3)
    #pragma unroll
    for (int i = 0; i < 4; ++i){
      int row = wm * 128 + (4 + i) * 16 + c;
      af[i] = *(const bf16x8*)(Asl + row * 32 + ((g ^ ((row >> 1) & 3)) << 3));
    }
    if (kt < 21) stageB(kt + 3);
    __builtin_amdgcn_s_barrier();
    asm volatile("s_waitcnt lgkmcnt(0)" ::: "memory");
    __builtin_amdgcn_sched_barrier(0);
    __builtin_amdgcn_s_setprio(1);
    #pragma unroll
    for (int i = 0; i < 4; ++i)
      #pragma unroll
      for (int ns = 0; ns < 4; ++ns)
        acc[4 + i][ns] = mfma16(af[i], bfr[ns], acc[4 + i][ns]);
    __builtin_amdgcn_s_setprio(0);
    // drain exactly B(kt+1) (oldest 2 of 10 outstanding); tail 2/0
    if (kt <= 20)      asm volatile("s_waitcnt vmcnt(8)" ::: "memory");
    else if (kt == 21) asm volatile("s_waitcnt vmcnt(2)" ::: "memory");
    else if (kt == 22) asm volatile("s_waitcnt vmcnt(0)" ::: "memory");
    __builtin_amdgcn_s_barrier();
  }

  // ---- epilogue: wave-private 8KB LDS chunk -> coalesced 16B stores
  int n0g = n0 + wn * 64;                    // 64 cols = exactly one head
  const float* bias = (mat == 0) ? bq : (mat == 1 ? bk : bv);
  float bb[4];
  #pragma unroll
  for (int ns = 0; ns < 4; ++ns) bb[ns] = bias[n0g + ns * 16 + c];
  short* chunk = smem + wv * 4096;           // 8 KB per wave
  int hq = n0g >> 6;

  if (mat < 2){
    short* O = (mat == 0) ? Qw : Kw;
    float scl = (mat == 0) ? QSCALE : 1.0f;
    #pragma unroll
    for (int sp = 0; sp < 2; ++sp){
      #pragma unroll
      for (int msl = 0; msl < 4; ++msl){
        #pragma unroll
        for (int ns = 0; ns < 4; ++ns){
          int col = ns * 16 + c;             // hs
          #pragma unroll
          for (int i = 0; i < 4; ++i){
            int row = msl * 16 + g * 4 + i;  // s-local 0..63
            chunk[row * 64 + (((col >> 3) ^ (row & 7)) << 3) + (col & 7)] =
                (short)f2bf((acc[sp * 4 + msl][ns][i] + bb[ns]) * scl);
          }
        }
      }
      asm volatile("s_waitcnt lgkmcnt(0)" ::: "memory");
      __builtin_amdgcn_sched_barrier(0);
      #pragma unroll
      for (int rr = 0; rr < 8; ++rr){
        int row = rr * 8 + (l >> 3);         // 0..63, all 64 rows covered
        int slot = l & 7;
        bf16x8 v = *(const bf16x8*)(chunk + row * 64 + ((slot ^ (row & 7)) << 3));
        int m = m0 + wm * 128 + sp * 64 + row;
        int b = m >> 9, s2 = m & 511;
        *(bf16x8*)(O + (((long)(b * NH + hq) * NS + s2) << 6) + slot * 8) = v;
      }
      if (sp == 0){ asm volatile("s_waitcnt lgkmcnt(0)" ::: "memory"); }
    }
  } else {
    #pragma unroll
    for (int sp = 0; sp < 2; ++sp){
      #pragma unroll
      for (int msl = 0; msl < 4; ++msl){
        #pragma unroll
        for (int ns = 0; ns < 4; ++ns){
          int hs = ns * 16 + c;              // row 0..63
          #pragma unroll
          for (int i = 0; i < 4; ++i){
            int col = msl * 16 + g * 4 + i;  // s-local 0..63
            chunk[hs * 64 + (((col >> 3) ^ (hs & 7)) << 3) + (col & 7)] =
                (short)f2bf(acc[sp * 4 + msl][ns][i] + bb[ns]);
          }
        }
      }
      asm volatile("s_waitcnt lgkmcnt(0)" ::: "memory");
      __builtin_amdgcn_sched_barrier(0);
      int mbase = m0 + wm * 128 + sp * 64;   // 64-aligned, never crosses b
      int b = mbase >> 9, s0 = mbase & 511;
      #pragma unroll
      for (int rr = 0; rr < 8; ++rr){
        int hs = rr * 8 + (l >> 3);
        int slot = l & 7;
        bf16x8 v = *(const bf16x8*)(chunk + hs * 64 + ((slot ^ (hs & 7)) << 3));
        *(bf16x8*)(Vtw + (long)((b * NH + hq) * 64 + hs) * NS + s0 + slot * 8) = v;
      }
      if (sp == 0){ asm volatile("s_waitcnt lgkmcnt(0)" ::: "memory"); }
    }
  }
}

// ---------------- attention v4: v3 + T15 att[2] double-pipeline + setprio.
// Per chunk: {ds_read K(ch+1) | softmax(ch) | QK-mfma(ch+1) | pack(ch) | PV(ch)}
// — MFMA pipe overlaps softmax/pack VALU. All array indices unroll-static. ----
__global__ __launch_bounds__(512, 1)
void attn_kernel(const short* __restrict__ Qw, const short* __restrict__ Kw,
                 const short* __restrict__ Vtw, float* __restrict__ out){
  extern __shared__ char smem[];
  short* Ks = (short*)smem;              // [512][64] bf16, swizzled rows 128B, 64 KB
  short* Vs = (short*)(smem + 65536);    // [64][512] bf16, swizzled rows 1KB, 64 KB

  int bh = blockIdx.x;                   // 768 blocks
  int t = threadIdx.x, wv = t >> 6, l = t & 63;
  int lam = l & 31, hi = l >> 5;
  int r7 = lam & 7;

  const short* Kb = Kw  + (long)bh * NS * NHS;
  const short* Vb = Vtw + (long)bh * NS * NHS;

  // stage K [key][d] and Vt [d][key] once, 128 chunks of 1KB over 8 waves
  #pragma unroll
  for (int it = 0; it < 8; ++it){
    int chunk = it * 8 + wv;             // wave-uniform, 0..63
    {
      int idx = chunk * 64 + l;
      int row = idx >> 3, slot = idx & 7;
      const short* gk = Kb + row * 64 + ((slot ^ (row & 7)) * 8);
      __builtin_amdgcn_global_load_lds((const GAS unsigned int*)gk,
                                       (LAS unsigned int*)(Ks + chunk * 512), 16, 0, 0);
    }
    {
      int row = chunk, slot = l;         // one chunk = one d-row
      const short* gv = Vb + (long)row * NS + (((slot & 56) | ((slot & 7) ^ (row & 7))) * 8);
      __builtin_amdgcn_global_load_lds((const GAS unsigned int*)gv,
                                       (LAS unsigned int*)(Vs + chunk * 512), 16, 0, 0);
    }
  }
  __syncthreads();

  int b = bh / NH, h = bh - b * NH;
  float* outb = out + (long)b * NS * ND + (long)h * 64;

  for (int qt = 0; qt < 2; ++qt){
    int q0 = wv * 64 + qt * 32;
    // Q as B-operand: B[k=hi*8+j][col=q=lam], d = dk*16 + hi*8 + j
    const short* Qb = Qw + (((long)bh * NS + q0 + lam) << 6) + hi * 8;
    bf16x8 qf[4];
    #pragma unroll
    for (int dk = 0; dk < 4; ++dk) qf[dk] = *(const bf16x8*)(Qb + dk * 16);

    f32x16 o0, o1;                       // O[q=q0+lam][d=(reg&3)+8*(reg>>2)+4*hi+32*dh]
    #pragma unroll
    for (int j = 0; j < 16; ++j){ o0[j] = 0.f; o1[j] = 0.f; }
    float m_run = -1e30f, lsum = 0.f;

    // ---- T15 pipeline state: two score tiles + two K-frag sets
    f32x16 s2[2];
    bf16x8 kfr[2][4];
    {
      const char* kb = (const char*)Ks + lam * 128;       // chunk 0
      #pragma unroll
      for (int dk = 0; dk < 4; ++dk)
        kfr[0][dk] = *(const bf16x8*)(kb + (((hi + 2 * dk) ^ r7) << 4));
      #pragma unroll
      for (int j = 0; j < 16; ++j) s2[0][j] = 0.f;
      __builtin_amdgcn_s_setprio(1);
      #pragma unroll
      for (int dk = 0; dk < 4; ++dk) s2[0] = mfma32(kfr[0][dk], qf[dk], s2[0]);
      __builtin_amdgcn_s_setprio(0);
    }

    #pragma unroll
    for (int ch = 0; ch < 16; ++ch){
      const int cur = ch & 1, nxt = cur ^ 1;

      // (1) ds_read next chunk's K-frags (latency hidden under softmax VALU)
      if (ch < 15){
        const char* kb = (const char*)Ks + ((ch + 1) * 32 + lam) * 128;
        #pragma unroll
        for (int dk = 0; dk < 4; ++dk)
          kfr[nxt][dk] = *(const bf16x8*)(kb + (((hi + 2 * dk) ^ r7) << 4));
      }

      // (2) softmax on s2[cur] (defer-max THR=8; deferred 1/sum)
      float t8[8], t4[4];
      #pragma unroll
      for (int j = 0; j < 8; ++j) t8[j] = fmaxf(s2[cur][j], s2[cur][j + 8]);
      #pragma unroll
      for (int j = 0; j < 4; ++j) t4[j] = fmaxf(t8[j], t8[j + 4]);
      float m1 = fmaxf(fmaxf(t4[0], t4[1]), fmaxf(t4[2], t4[3]));
      float pmax = fmaxf(m1, __shfl_xor(m1, 32));
      if (__any(pmax > m_run + 8.0f)){
        float mnew = fmaxf(m_run, pmax);
        float cf = exp2f(m_run - mnew);
        lsum *= cf;
        #pragma unroll
        for (int j = 0; j < 16; ++j){ o0[j] *= cf; o1[j] *= cf; }
        m_run = mnew;
      }
      float p[16];
      #pragma unroll
      for (int j = 0; j < 16; ++j) p[j] = exp2f(s2[cur][j] - m_run);
      float a8[8], a4[4];
      #pragma unroll
      for (int j = 0; j < 8; ++j) a8[j] = p[j] + p[j + 8];
      #pragma unroll
      for (int j = 0; j < 4; ++j) a4[j] = a8[j] + a8[j + 4];
      lsum += (a4[0] + a4[1]) + (a4[2] + a4[3]);

      // (3) issue next chunk's QK^T — MFMA pipe overlaps the pack VALU below
      if (ch < 15){
        #pragma unroll
        for (int j = 0; j < 16; ++j) s2[nxt][j] = 0.f;
        __builtin_amdgcn_s_setprio(1);
        #pragma unroll
        for (int dk = 0; dk < 4; ++dk) s2[nxt] = mfma32(kfr[nxt][dk], qf[dk], s2[nxt]);
        __builtin_amdgcn_s_setprio(0);
      }

      // (4) P -> bf16 fragments, single-partner exchange (lane ^ 32)
      unsigned int w[8];
      #pragma unroll
      for (int rr = 0; rr < 8; ++rr) w[rr] = cvtpk(p[2 * rr], p[2 * rr + 1]);
      unsigned int y0 = (unsigned int)__shfl_xor((int)(hi ? w[0] : w[2]), 32);
      unsigned int y1 = (unsigned int)__shfl_xor((int)(hi ? w[1] : w[3]), 32);
      unsigned int y2 = (unsigned int)__shfl_xor((int)(hi ? w[4] : w[6]), 32);
      unsigned int y3 = (unsigned int)__shfl_xor((int)(hi ? w[5] : w[7]), 32);
      u32x4 fa, fb;
      if (hi){
        fa[0] = y0;   fa[1] = y1;   fa[2] = w[2]; fa[3] = w[3];   // keys 8..15
        fb[0] = y2;   fb[1] = y3;   fb[2] = w[6]; fb[3] = w[7];   // keys 24..31
      } else {
        fa[0] = w[0]; fa[1] = w[1]; fa[2] = y0;   fa[3] = y1;     // keys 0..7
        fb[0] = w[4]; fb[1] = w[5]; fb[2] = y2;   fb[3] = y3;     // keys 16..23
      }
      bf16x8 pa = u2b(fa), pb = u2b(fb);

      // (5) PV (swapped): o[dh] += mfma32(V^T-frag, P-frag)
      const char* vb0 = (const char*)Vs + lam * 1024;          // d = lam
      const char* vb1 = (const char*)Vs + (32 + lam) * 1024;   // d = 32+lam
      int sl0 = ch * 4 + hi, sl1 = ch * 4 + 2 + hi;
      int sw0 = ((sl0 & 56) | ((sl0 & 7) ^ r7)) << 4;
      int sw1 = ((sl1 & 56) | ((sl1 & 7) ^ r7)) << 4;
      bf16x8 v00 = *(const bf16x8*)(vb0 + sw0);
      bf16x8 v01 = *(const bf16x8*)(vb0 + sw1);
      bf16x8 v10 = *(const bf16x8*)(vb1 + sw0);
      bf16x8 v11 = *(const bf16x8*)(vb1 + sw1);
      __builtin_amdgcn_s_setprio(1);
      o0 = mfma32(v00, pa, o0);
      o0 = mfma32(v01, pb, o0);
      o1 = mfma32(v10, pa, o1);
      o1 = mfma32(v11, pb, o1);
      __builtin_amdgcn_s_setprio(0);
    }

    // ---- epilogue: combine l across partner, deferred 1/sum, float4 stores
    float lt = lsum + __shfl_xor(lsum, 32);
    float invl = 1.0f / lt;
    float* orow = outb + (long)(q0 + lam) * ND;
    #pragma unroll
    for (int r = 0; r < 4; ++r){
      f4 u0, u1;
      #pragma unroll
      for (int jj = 0; jj < 4; ++jj){
        u0[jj] = o0[4 * r + jj] * invl;
        u1[jj] = o1[4 * r + jj] * invl;
      }
      *(f4*)(orow + 4 * hi + 8 * r)      = u0;   // d = 4hi+8r+{0..3}
      *(f4*)(orow + 32 + 4 * hi + 8 * r) = u1;   // d = 32+4hi+8r+{0..3}
    }
  }
}

// ---------------- launch ----------------
extern "C" void kernel_launch(void* const* d_in, const int* in_sizes, int n_in,
                              void* d_out, int out_size, void* d_ws, size_t ws_size,
                              hipStream_t stream){
  const float* from_t = (const float*)d_in[0];
  const float* to_t   = (const float*)d_in[1];
  const float* Wq = (const float*)d_in[2];
  const float* bq = (const float*)d_in[3];
  const float* Wk = (const float*)d_in[4];
  const float* bk = (const float*)d_in[5];
  const float* Wv = (const float*)d_in[6];
  const float* bv = (const float*)d_in[7];

  short* Wt  = (short*)d_ws;                 // 1769472 bf16
  short* Qw  = Wt  + 1769472;                // 25165824
  short* Kw  = Qw  + 25165824;               // 25165824
  short* Vtw = Kw  + 25165824;               // 25165824  (total ~147 MB)

  cvt_w<<<6912, 256, 0, stream>>>(Wq, Wk, Wv, Wt);
  qkv_gemm<<<1152, 512, 0, stream>>>(from_t, to_t, Wt, bq, bk, bv, Qw, Kw, Vtw);
  attn_kernel<<<768, 512, 131072, stream>>>(Qw, Kw, Vtw, (float*)d_out);
}